// Round 6
// baseline (58.365 us; speedup 1.0000x reference)
//
#include <hip/hip_runtime.h>
#include <hip/hip_bf16.h>

// ST-GCN spatial graph conv — chunked two-stage MFMA pipeline (bf16, f32 accum).
//
//   prepass (d_ws):  Wbf[192 o][64 ci] bf16; Ahat[32 w][104 khat] bf16 (zero-pad
//                    v>=25, khat>=96); bout[64 c][32 w] f32 = sum_k b[kc]*sum_v A[k,v,w]
//                    (bias folded out of F -> constant out-init).
//   main: block = (n, 12 t's), 512 thr. W-frags/Ahat-frags/bout loaded ONCE per
//   block from ws (L2). Loop 6 chunks of 2t:
//     stage1 (all-register): F^T[tv][kc] = X^T @ W^T   (x frags prefetched chunk-ahead)
//     F -> Fs LDS (double-buffered, XOR-swizzled) -> ONE barrier
//     stage2: out_t^T[w][c] = Ahat[w][khat] @ F_t[khat][c]  (+bout init)
//   LDS = Fs dbuf only: 2 x 24 KB. No staging barrier, no Ws/As LDS.

#define CIN   64
#define T_    300
#define V_    25
#define OC    192
#define COUT  64
#define TB    12
#define NCHUNK 6
#define NBLK  (32 * (T_ / TB))   // 800

#define WS_W    0        // 24576 B : bf16 W[o][ci]
#define WS_AS   24576    // 6656  B : bf16 Ahat[32][104]
#define WS_BOUT 31232    // 8192  B : f32 bout[64][32]
#define WS_BYTES 39424

typedef short  bf16x8 __attribute__((ext_vector_type(8)));
typedef float  f32x4  __attribute__((ext_vector_type(4)));
typedef unsigned int u32x2 __attribute__((ext_vector_type(2)));

__device__ __forceinline__ unsigned short cvt_bf16(float f) {
    union { __hip_bfloat16 h; unsigned short u; } cv;
    cv.h = __float2bfloat16(f);
    return cv.u;
}

// ---------------- prepass: build ws images ----------------
__global__ void gcn_prep(const float* __restrict__ W, const float* __restrict__ bias,
                         const float* __restrict__ A, unsigned char* __restrict__ ws)
{
    const int tid = blockIdx.x * 256 + threadIdx.x;   // grid 16*256 = 4096
    for (int i = tid; i < OC * CIN; i += 4096)
        reinterpret_cast<unsigned short*>(ws + WS_W)[i] = cvt_bf16(W[i]);
    for (int i = tid; i < 32 * 104; i += 4096) {
        const int wq = i / 104, kh = i % 104;
        const int k = kh >> 5, v = kh & 31;
        const float val = (kh < 96 && wq < V_ && v < V_) ? A[k * 625 + v * 25 + wq] : 0.f;
        reinterpret_cast<unsigned short*>(ws + WS_AS)[i] = cvt_bf16(val);
    }
    for (int i = tid; i < 64 * 32; i += 4096) {
        const int c = i >> 5, w = i & 31;
        float s = 0.f;
        if (w < V_) {
            for (int k = 0; k < 3; ++k) {
                float sa = 0.f;
                for (int v = 0; v < V_; ++v) sa += A[k * 625 + v * 25 + w];
                s += bias[k * 64 + c] * sa;
            }
        }
        reinterpret_cast<float*>(ws + WS_BOUT)[i] = s;
    }
}

// ---------------- main ----------------
__global__ __launch_bounds__(512, 4) void gcn_main(
    const float* __restrict__ x, const unsigned char* __restrict__ ws,
    float* __restrict__ out)
{
    __shared__ __align__(16) unsigned char smem[49152];   // Fs[2][192 kc][64 tv] bf16

    const int tid = threadIdx.x;
    const int bx  = blockIdx.x;
    const int n   = bx / (T_ / TB);
    const int t0  = (bx % (T_ / TB)) * TB;

    const int wv = tid >> 6, l = tid & 63, lr = l & 15, lq = l >> 4;
    const int m  = wv >> 1;              // stage-1 M-tile (tv rows m*16..+15)
    const int n0 = (wv & 1) * 6;         // stage-1 N-tile range
    const int mt = wv >> 2, nc = wv & 3; // stage-2 tile (w rows, c cols)

    // ---- per-block constants from ws (L2-hot), loaded once
    bf16x8 wfr[2][6];
    #pragma unroll
    for (int ks = 0; ks < 2; ++ks)
        #pragma unroll
        for (int j = 0; j < 6; ++j) {
            const int o = (n0 + j) * 16 + lr;
            wfr[ks][j] = *reinterpret_cast<const bf16x8*>(
                ws + WS_W + (o * CIN + ks * 32 + lq * 8) * 2);
        }
    bf16x8 afr2[3];
    #pragma unroll
    for (int ks = 0; ks < 3; ++ks)
        afr2[ks] = *reinterpret_cast<const bf16x8*>(
            ws + WS_AS + ((mt * 16 + lr) * 104 + ks * 32 + lq * 8) * 2);
    const int c  = nc * 16 + lr;
    const int w0 = mt * 16 + lq * 4;
    const f32x4 binit = *reinterpret_cast<const f32x4*>(ws + WS_BOUT + (c * 32 + w0) * 4);

    // ---- x base for this wave's stage-1 A-frag rows
    const int tt = m >> 1;                       // chunk-relative t
    const int v  = (m & 1) * 16 + lr;
    const int vc = v > 24 ? 24 : v;              // clamp; pad rows killed by Ahat zeros
    const float* xb = x + ((size_t)(n * CIN + lq * 8) * T_ + (t0 + tt)) * V_ + vc;

    // ---- prefetch chunk 0
    float xf[16];
    #pragma unroll
    for (int ks = 0; ks < 2; ++ks)
        #pragma unroll
        for (int e = 0; e < 8; ++e)
            xf[ks * 8 + e] = xb[(size_t)(ks * 32 + e) * (T_ * V_)];

    const int tvb = m * 16 + lq * 4;             // F-write col base

    for (int ch = 0; ch < NCHUNK; ++ch) {
        // convert current chunk's x to A-frags (forces wait on loads)
        bf16x8 afr1[2];
        #pragma unroll
        for (int ks = 0; ks < 2; ++ks)
            #pragma unroll
            for (int e = 0; e < 8; ++e)
                afr1[ks][e] = (short)cvt_bf16(xf[ks * 8 + e]);

        // prefetch next chunk (in flight across stage1+barrier+stage2)
        if (ch + 1 < NCHUNK) {
            const float* xn = xb + (ch + 1) * 2 * V_;
            #pragma unroll
            for (int ks = 0; ks < 2; ++ks)
                #pragma unroll
                for (int e = 0; e < 8; ++e)
                    xf[ks * 8 + e] = xn[(size_t)(ks * 32 + e) * (T_ * V_)];
        }

        // ---- stage 1: all-register MFMA
        f32x4 acc[6];
        #pragma unroll
        for (int i = 0; i < 6; ++i) acc[i] = (f32x4){0.f, 0.f, 0.f, 0.f};
        #pragma unroll
        for (int ks = 0; ks < 2; ++ks)
            #pragma unroll
            for (int j = 0; j < 6; ++j)
                acc[j] = __builtin_amdgcn_mfma_f32_16x16x32_bf16(afr1[ks], wfr[ks][j], acc[j], 0, 0, 0);

        // ---- write F to Fs[ch&1], swizzled
        const unsigned fsb = (unsigned)(ch & 1) * 24576u;
        #pragma unroll
        for (int j = 0; j < 6; ++j) {
            const int kc = (n0 + j) * 16 + lr;
            u32x2 pk;
            pk[0] = (unsigned)cvt_bf16(acc[j][0]) | ((unsigned)cvt_bf16(acc[j][1]) << 16);
            pk[1] = (unsigned)cvt_bf16(acc[j][2]) | ((unsigned)cvt_bf16(acc[j][3]) << 16);
            *reinterpret_cast<u32x2*>(
                smem + fsb + kc * 128 + ((((tvb >> 3) ^ (kc & 7)) << 4)) + (tvb & 7) * 2) = pk;
        }
        __syncthreads();   // the only barrier per chunk (dbuf covers reuse hazard)

        // ---- stage 2
        #pragma unroll
        for (int t = 0; t < 2; ++t) {
            f32x4 a2 = binit;
            #pragma unroll
            for (int ks = 0; ks < 3; ++ks) {
                const int kc = ks * 64 + c;
                const bf16x8 bfr = *reinterpret_cast<bf16x8*>(
                    smem + fsb + kc * 128 + ((((t * 4 + lq) ^ (kc & 7)) << 4)));
                a2 = __builtin_amdgcn_mfma_f32_16x16x32_bf16(afr2[ks], bfr, a2, 0, 0, 0);
            }
            float* op = out + ((size_t)(n * COUT + c) * T_ + (t0 + ch * 2 + t)) * V_;
            if (w0 + 3 < V_) {
                #pragma unroll
                for (int e = 0; e < 4; ++e) op[w0 + e] = a2[e];
            } else {
                #pragma unroll
                for (int e = 0; e < 4; ++e) if (w0 + e < V_) op[w0 + e] = a2[e];
            }
        }
    }
}

extern "C" void kernel_launch(void* const* d_in, const int* in_sizes, int n_in,
                              void* d_out, int out_size, void* d_ws, size_t ws_size,
                              hipStream_t stream) {
    const float* x    = (const float*)d_in[0];
    const float* W    = (const float*)d_in[1];
    const float* bias = (const float*)d_in[2];
    const float* A    = (const float*)d_in[3];
    float* out = (float*)d_out;
    unsigned char* ws = (unsigned char*)d_ws;   // needs WS_BYTES = 39424 B

    hipLaunchKernelGGL(gcn_prep, dim3(16), dim3(256), 0, stream, W, bias, A, ws);
    hipLaunchKernelGGL(gcn_main, dim3(NBLK), dim3(512), 0, stream, x, ws, out);
}